// Round 4
// baseline (536.588 us; speedup 1.0000x reference)
//
#include <hip/hip_runtime.h>
#include <math.h>

#define NB 4
#define SEQ 4096
#define DM 1024
#define NG 4
#define DI 512
#define NQS 1024
#define NKS 512
#define NHD 8
#define DHD 64

typedef unsigned int u32;
typedef unsigned short u16;
typedef __bf16 bf16x8 __attribute__((ext_vector_type(8)));
typedef float f32x4 __attribute__((ext_vector_type(4)));

__device__ __forceinline__ float bf2f(u16 u) { return __uint_as_float(((u32)u) << 16); }
__device__ __forceinline__ u16 f2bf(float f) {
  u32 u = __float_as_uint(f);
  u32 r = (u + 0x7FFFu + ((u >> 16) & 1u)) >> 16;
  return (u16)r;
}

// ---------------- fp32 -> bf16 bulk convert ----------------
__global__ __launch_bounds__(256) void convert_bf16(const float* __restrict__ src,
                                                    u16* __restrict__ dst, int n4) {
  int i = blockIdx.x * 256 + threadIdx.x;
  if (i < n4) {
    float4 v = ((const float4*)src)[i];
    ushort4 o;
    o.x = f2bf(v.x); o.y = f2bf(v.y); o.z = f2bf(v.z); o.w = f2bf(v.w);
    ((ushort4*)dst)[i] = o;
  }
}

// ---------------- router: logits[b][g][n] for q and kv (fp32 — selection exactness) ----------------
__global__ __launch_bounds__(256) void router_kernel(
    const float* __restrict__ x, const float* __restrict__ wqr,
    const float* __restrict__ wkvr, float* __restrict__ qlog,
    float* __restrict__ kvlog) {
  __shared__ float wsm[8192];
  int tid = threadIdx.x;
  for (int k = tid; k < 8192; k += 256)
    wsm[k] = (k < 4096) ? wqr[k] : wkvr[k - 4096];
  __syncthreads();
  int widx = blockIdx.x * 4 + (tid >> 6);
  int lane = tid & 63;
  int b = widx >> 12, tok = widx & 4095;
  const float4* xr = (const float4*)(x + ((size_t)(b * SEQ + tok)) * DM);
  float4 xv[4];
#pragma unroll
  for (int i = 0; i < 4; i++) xv[i] = xr[i * 64 + lane];
  float accs[8];
#pragma unroll
  for (int r = 0; r < 8; r++) {
    const float4* wr = (const float4*)(wsm + r * 1024);
    float a = 0.f;
#pragma unroll
    for (int i = 0; i < 4; i++) {
      float4 w4 = wr[i * 64 + lane];
      a += xv[i].x * w4.x + xv[i].y * w4.y + xv[i].z * w4.z + xv[i].w * w4.w;
    }
    accs[r] = a;
  }
#pragma unroll
  for (int r = 0; r < 8; r++) {
    float a = accs[r];
#pragma unroll
    for (int off = 32; off >= 1; off >>= 1) a += __shfl_xor(a, off);
    if (lane == 0) {
      if (r < 4) qlog[((b << 2) | r) * SEQ + tok] = a;
      else kvlog[((b << 2) | (r - 4)) * SEQ + tok] = a;
    }
  }
}

// ---------------- top-k radix select per (b,g) ----------------
__global__ __launch_bounds__(256) void topk_kernel(
    const float* __restrict__ logits, int K, int* __restrict__ out_idx,
    float* __restrict__ out_score, float* __restrict__ counts) {
  __shared__ u32 keys[4096];
  __shared__ int eqlist[2048];
  __shared__ int scnt[4];
  __shared__ int s_gt, s_eq;
  int bg = blockIdx.x;
  int tid = threadIdx.x;
  const float* L = logits + bg * 4096;
  for (int e = tid; e < 4096; e += 256) {
    u32 u = __float_as_uint(L[e]);
    keys[e] = (u >> 31) ? ~u : (u | 0x80000000u);
  }
  if (tid == 0) { s_gt = 0; s_eq = 0; }
  __syncthreads();
  u32 prefix = 0;
  int remaining = K;
  for (int bit = 31; bit >= 0; --bit) {
    u32 want = prefix | (1u << bit);
    u32 mask = ~((1u << bit) - 1u);
    int c = 0;
    for (int e = tid; e < 4096; e += 256) c += ((keys[e] & mask) == want) ? 1 : 0;
#pragma unroll
    for (int off = 32; off >= 1; off >>= 1) c += __shfl_xor(c, off);
    if ((tid & 63) == 0) scnt[tid >> 6] = c;
    __syncthreads();
    int total = scnt[0] + scnt[1] + scnt[2] + scnt[3];
    if (total >= remaining) prefix = want;
    else remaining -= total;
    __syncthreads();
  }
  u32 T = prefix;
  for (int e = tid; e < 4096; e += 256) {
    u32 k = keys[e];
    if (k > T) {
      int pos = atomicAdd(&s_gt, 1);
      out_idx[bg * K + pos] = e;
      float v = L[e];
      out_score[bg * K + pos] = 1.0f / (1.0f + __expf(-v));
      if (counts) atomicAdd(&counts[(bg >> 2) * SEQ + e], 1.0f);
    } else if (k == T) {
      int p = atomicAdd(&s_eq, 1);
      if (p < 2048) eqlist[p] = e;
    }
  }
  __syncthreads();
  int gt = s_gt;
  int eq = min(s_eq, 2048);
  int need = K - gt;
  for (int i = tid; i < eq; i += 256) {
    int my = eqlist[i];
    int rank = 0;
    for (int j = 0; j < eq; j++) rank += (eqlist[j] < my) ? 1 : 0;
    if (rank < need) {
      int pos = gt + rank;
      out_idx[bg * K + pos] = my;
      float v = L[my];
      out_score[bg * K + pos] = 1.0f / (1.0f + __expf(-v));
      if (counts) atomicAdd(&counts[(bg >> 2) * SEQ + my], 1.0f);
    }
  }
}

// ---------------- shared MFMA GEMM core: 128x128 tile, BK=64, swizzled LDS ----------------
struct Ptr4 { const u16* p[4]; };

__device__ __forceinline__ void mfma_core(Ptr4 A, Ptr4 B, u16* Asm, u16* Bsm,
                                          int ktiles, int tid, f32x4 (&acc)[4][4]) {
  int w = tid >> 6, lane = tid & 63;
  int col = lane & 15, quad = lane >> 4;
  int wr = w >> 1, wc = w & 1;
  for (int kt = 0; kt < ktiles; kt++) {
#pragma unroll
    for (int r = 0; r < 4; r++) {
      char* ldsA = (char*)Asm + (r * 256 + w * 64) * 16;
      __builtin_amdgcn_global_load_lds(
          (const __attribute__((address_space(1))) void*)(A.p[r] + kt * 64),
          (__attribute__((address_space(3))) void*)ldsA, 16, 0, 0);
    }
#pragma unroll
    for (int r = 0; r < 4; r++) {
      char* ldsB = (char*)Bsm + (r * 256 + w * 64) * 16;
      __builtin_amdgcn_global_load_lds(
          (const __attribute__((address_space(1))) void*)(B.p[r] + kt * 64),
          (__attribute__((address_space(3))) void*)ldsB, 16, 0, 0);
    }
    __syncthreads();
#pragma unroll
    for (int k04 = 0; k04 < 8; k04 += 4) {
      bf16x8 af[4], bfr[4];
#pragma unroll
      for (int t = 0; t < 4; t++) {
        int rowa = wr * 64 + t * 16 + col;
        int sp = (quad + k04) ^ (col & 7);
        af[t] = *(const bf16x8*)((const char*)Asm + (rowa * 8 + sp) * 16);
        int rowb = wc * 64 + t * 16 + col;
        bfr[t] = *(const bf16x8*)((const char*)Bsm + (rowb * 8 + sp) * 16);
      }
#pragma unroll
      for (int t = 0; t < 4; t++)
#pragma unroll
        for (int u = 0; u < 4; u++)
          acc[t][u] = __builtin_amdgcn_mfma_f32_16x16x32_bf16(af[t], bfr[u], acc[t][u], 0, 0, 0);
    }
    __syncthreads();
  }
}

// ---------------- q projection: qbuf[bg][1024][512] = gather(xbf) @ wq^T ----------------
__global__ __launch_bounds__(256) void gemm_qproj(
    const u16* __restrict__ xbf, const int* __restrict__ qidx,
    const u16* __restrict__ wqbf, u16* __restrict__ qbuf) {
  int bg = blockIdx.z, b = bg >> 2, g = bg & 3;
  int row0 = blockIdx.y * 128, col0 = blockIdx.x * 128;
  __shared__ __align__(16) u16 Asm[8192], Bsm[8192];
  __shared__ int ridx[128];
  int tid = threadIdx.x;
  if (tid < 128) ridx[tid] = qidx[bg * NQS + row0 + tid];
  __syncthreads();
  Ptr4 A, B;
#pragma unroll
  for (int r = 0; r < 4; r++) {
    int G = r * 256 + tid;
    int row = G >> 3;
    int seg = (G & 7) ^ (row & 7);
    A.p[r] = xbf + ((size_t)b * SEQ + ridx[row]) * DM + seg * 8;
    B.p[r] = wqbf + ((size_t)g * DI + col0 + row) * DM + seg * 8;
  }
  f32x4 acc[4][4] = {};
  mfma_core(A, B, Asm, Bsm, DM / 64, tid, acc);
  int w = tid >> 6, lane = tid & 63;
  int col = lane & 15, quad = lane >> 4;
  int wr = w >> 1, wc = w & 1;
#pragma unroll
  for (int t = 0; t < 4; t++)
#pragma unroll
    for (int u = 0; u < 4; u++)
#pragma unroll
      for (int r = 0; r < 4; r++) {
        int rowg = row0 + wr * 64 + t * 16 + quad * 4 + r;
        int colg = col0 + wc * 64 + u * 16 + col;
        qbuf[((size_t)bg * NQS + rowg) * DI + colg] = f2bf(acc[t][u][r]);
      }
}

// ---------------- kv projection: K -> kbuf, V^T (scaled) -> vtbuf[bg][h][64][512] ----------------
__global__ __launch_bounds__(256) void gemm_kvproj(
    const u16* __restrict__ xbf, const int* __restrict__ kvidx,
    const u16* __restrict__ wkvbf, const float* __restrict__ kvscore,
    u16* __restrict__ kbuf, u16* __restrict__ vtbuf) {
  int bg = blockIdx.z, b = bg >> 2, g = bg & 3;
  int row0 = blockIdx.y * 128, col0 = blockIdx.x * 128;
  __shared__ __align__(16) u16 Asm[8192], Bsm[8192];
  __shared__ int ridx[128];
  int tid = threadIdx.x;
  if (tid < 128) ridx[tid] = kvidx[bg * NKS + row0 + tid];
  __syncthreads();
  Ptr4 A, B;
#pragma unroll
  for (int r = 0; r < 4; r++) {
    int G = r * 256 + tid;
    int row = G >> 3;
    int seg = (G & 7) ^ (row & 7);
    A.p[r] = xbf + ((size_t)b * SEQ + ridx[row]) * DM + seg * 8;
    B.p[r] = wkvbf + ((size_t)g * (2 * DI) + col0 + row) * DM + seg * 8;
  }
  f32x4 acc[4][4] = {};
  mfma_core(A, B, Asm, Bsm, DM / 64, tid, acc);
  int w = tid >> 6, lane = tid & 63;
  int col = lane & 15, quad = lane >> 4;
  int wr = w >> 1, wc = w & 1;
  if (col0 < DI) {
#pragma unroll
    for (int t = 0; t < 4; t++)
#pragma unroll
      for (int u = 0; u < 4; u++)
#pragma unroll
        for (int r = 0; r < 4; r++) {
          int rowg = row0 + wr * 64 + t * 16 + quad * 4 + r;
          int colg = col0 + wc * 64 + u * 16 + col;
          kbuf[((size_t)bg * NKS + rowg) * DI + colg] = f2bf(acc[t][u][r]);
        }
  } else {
#pragma unroll
    for (int t = 0; t < 4; t++)
#pragma unroll
      for (int r = 0; r < 4; r++) {
        int rowg = row0 + wr * 64 + t * 16 + quad * 4 + r;  // key index 0..511
        float sc = kvscore[bg * NKS + rowg];
#pragma unroll
        for (int u = 0; u < 4; u++) {
          int vc = col0 - DI + wc * 64 + u * 16 + col;  // 0..511
          int h = vc >> 6, d = vc & 63;
          vtbuf[(((size_t)bg * NHD + h) * DHD + d) * NKS + rowg] =
              f2bf(acc[t][u][r] * sc);
        }
      }
  }
}

// ---------------- out projection + scaled scatter-add ----------------
__global__ __launch_bounds__(256) void gemm_outproj(
    const u16* __restrict__ obuf, const u16* __restrict__ woutbf,
    const int* __restrict__ qidx, const float* __restrict__ qscore,
    float* __restrict__ dout) {
  int bg = blockIdx.z, b = bg >> 2, g = bg & 3;
  int row0 = blockIdx.y * 128, col0 = blockIdx.x * 128;
  __shared__ __align__(16) u16 Asm[8192], Bsm[8192];
  int tid = threadIdx.x;
  Ptr4 A, B;
#pragma unroll
  for (int r = 0; r < 4; r++) {
    int G = r * 256 + tid;
    int row = G >> 3;
    int seg = (G & 7) ^ (row & 7);
    A.p[r] = obuf + ((size_t)bg * NQS + row0 + row) * DI + seg * 8;
    B.p[r] = woutbf + ((size_t)g * DM + col0 + row) * DI + seg * 8;
  }
  f32x4 acc[4][4] = {};
  mfma_core(A, B, Asm, Bsm, DI / 64, tid, acc);
  int w = tid >> 6, lane = tid & 63;
  int col = lane & 15, quad = lane >> 4;
  int wr = w >> 1, wc = w & 1;
#pragma unroll
  for (int t = 0; t < 4; t++)
#pragma unroll
    for (int r = 0; r < 4; r++) {
      int rowg = row0 + wr * 64 + t * 16 + quad * 4 + r;
      float sc = qscore[bg * NQS + rowg];
      int tok = qidx[bg * NQS + rowg];
      float* orow = dout + ((size_t)b * SEQ + tok) * DM;
#pragma unroll
      for (int u = 0; u < 4; u++) {
        int colg = col0 + wc * 64 + u * 16 + col;
        atomicAdd(&orow[colg], acc[t][u][r] * sc);
      }
    }
}

// ---------------- MFMA flash attention v2: no K/V LDS, null-key init, 4 chunks ----------------
// B-fragments of QK^T (K rows) and PV (V^T rows) are loaded directly from global;
// only the P (C-layout -> A-layout) transpose goes through per-wave swizzled LDS.
#define SM_SC 0.1803368801033677f  // 0.125 * log2(e)

__global__ __launch_bounds__(256) void attn_mfma(
    const u16* __restrict__ qbuf, const u16* __restrict__ kbuf,
    const u16* __restrict__ vtbuf, const float* __restrict__ null_kv,
    u16* __restrict__ obuf) {
  int qt = blockIdx.x;  // 0..15
  int h = blockIdx.y;   // 0..7
  int bg = blockIdx.z;  // 0..15
  int g = bg & 3;
  int tid = threadIdx.x;
  int w = tid >> 6, lane = tid & 63;
  int col = lane & 15, quad = lane >> 4;

  // per-wave P slab: [16 rows][16 granules of 8 u16], granule-swizzled
  __shared__ __align__(16) u16 Ps[4 * 256 * 8];  // 16 KB

  // Q A-fragments (row = col of this wave's 16 q-rows)
  int q0 = qt * 64 + w * 16;
  const u16* qp = qbuf + ((size_t)bg * NQS + q0 + col) * DI + h * DHD + quad * 8;
  bf16x8 qa0 = *(const bf16x8*)qp;
  bf16x8 qa1 = *(const bf16x8*)(qp + 32);

  // ---- null-key init: m = q . k_null (raw), l = 1, O = v_null ----
  const float* nk = null_kv + ((0 * NG + g) * NHD + h) * DHD;
  const float* nv = null_kv + ((1 * NG + g) * NHD + h) * DHD;
  bf16x8 kn0, kn1;
#pragma unroll
  for (int j = 0; j < 8; j++) {
    ((u16*)&kn0)[j] = f2bf(nk[quad * 8 + j]);
    ((u16*)&kn1)[j] = f2bf(nk[32 + quad * 8 + j]);
  }
  f32x4 sn = {0.f, 0.f, 0.f, 0.f};
  sn = __builtin_amdgcn_mfma_f32_16x16x32_bf16(qa0, kn0, sn, 0, 0, 0);
  sn = __builtin_amdgcn_mfma_f32_16x16x32_bf16(qa1, kn1, sn, 0, 0, 0);

  f32x4 oacc[4];
  float m_run[4], l_run[4];
#pragma unroll
  for (int t = 0; t < 4; t++) {
    float v = nv[t * 16 + col];
#pragma unroll
    for (int r = 0; r < 4; r++) oacc[t][r] = v;
  }
#pragma unroll
  for (int r = 0; r < 4; r++) { m_run[r] = sn[r]; l_run[r] = 1.f; }

  const u16* kb_base = kbuf + (size_t)bg * NKS * DI + h * DHD;
  const u16* vt_base = vtbuf + (((size_t)bg * NHD + h) * DHD) * NKS;

  for (int c = 0; c < 4; c++) {
    int base = c * 128;
    // ---- S = Q K^T : 8 tiles of 16 keys, K B-frags direct from global ----
    float sreg[8][4];
#pragma unroll
    for (int t = 0; t < 8; t++) {
      const u16* kp = kb_base + (size_t)(base + t * 16 + col) * DI + quad * 8;
      bf16x8 kb0 = *(const bf16x8*)kp;
      bf16x8 kb1 = *(const bf16x8*)(kp + 32);
      f32x4 s = {0.f, 0.f, 0.f, 0.f};
      s = __builtin_amdgcn_mfma_f32_16x16x32_bf16(qa0, kb0, s, 0, 0, 0);
      s = __builtin_amdgcn_mfma_f32_16x16x32_bf16(qa1, kb1, s, 0, 0, 0);
#pragma unroll
      for (int r = 0; r < 4; r++) sreg[t][r] = s[r];
    }

    // ---- online softmax (raw-score units; 0.125 folded into exp2 const) ----
    float alpha[4], rs[4];
#pragma unroll
    for (int r = 0; r < 4; r++) {
      float m = sreg[0][r];
#pragma unroll
      for (int t = 1; t < 8; t++) m = fmaxf(m, sreg[t][r]);
      m = fmaxf(m, __shfl_xor(m, 1));
      m = fmaxf(m, __shfl_xor(m, 2));
      m = fmaxf(m, __shfl_xor(m, 4));
      m = fmaxf(m, __shfl_xor(m, 8));
      float mnew = fmaxf(m_run[r], m);
      alpha[r] = exp2f((m_run[r] - mnew) * SM_SC);
      m_run[r] = mnew;
      rs[r] = 0.f;
    }
#pragma unroll
    for (int t = 0; t < 8; t++) {
      int key = t * 16 + col;
      int gg = key >> 3;
#pragma unroll
      for (int r = 0; r < 4; r++) {
        float p = exp2f((sreg[t][r] - m_run[r]) * SM_SC);
        rs[r] += p;
        int row = quad * 4 + r;
        int sp = (gg & 8) | ((gg ^ (row & 7)) & 7);
        Ps[((w * 256 + row * 16 + sp) << 3) | (key & 7)] = f2bf(p);
      }
    }
#pragma unroll
    for (int r = 0; r < 4; r++) {
      float s = rs[r];
      s += __shfl_xor(s, 1);
      s += __shfl_xor(s, 2);
      s += __shfl_xor(s, 4);
      s += __shfl_xor(s, 8);
      l_run[r] = l_run[r] * alpha[r] + s;
#pragma unroll
      for (int t = 0; t < 4; t++) oacc[t][r] *= alpha[r];
    }

    // ---- O += P V : A-frag from swizzled per-wave LDS, V B-frags from global ----
#pragma unroll
    for (int s = 0; s < 4; s++) {
      int gg = s * 4 + quad;
      int sp = (gg & 8) | ((gg ^ (col & 7)) & 7);
      bf16x8 pa = *(const bf16x8*)&Ps[(w * 256 + col * 16 + sp) << 3];
#pragma unroll
      for (int t = 0; t < 4; t++) {
        const u16* vp = vt_base + (size_t)(t * 16 + col) * NKS + base + s * 32 + quad * 8;
        bf16x8 vb = *(const bf16x8*)vp;
        oacc[t] = __builtin_amdgcn_mfma_f32_16x16x32_bf16(pa, vb, oacc[t], 0, 0, 0);
      }
    }
  }

  // ---- epilogue: O / l, store bf16 ----
  float inv[4];
#pragma unroll
  for (int r = 0; r < 4; r++) inv[r] = 1.0f / l_run[r];
#pragma unroll
  for (int t = 0; t < 4; t++) {
#pragma unroll
    for (int r = 0; r < 4; r++) {
      obuf[((size_t)bg * NQS + q0 + quad * 4 + r) * DI + h * DHD + t * 16 + col] =
          f2bf(oacc[t][r] * inv[r]);
    }
  }
}

// ---------------- finalize: mean + null-token fill ----------------
__global__ __launch_bounds__(256) void finalize_kernel(
    float* __restrict__ dout, const float* __restrict__ counts,
    const float* __restrict__ null_token) {
  int qd = blockIdx.x * 256 + threadIdx.x;
  int row = qd >> 8;
  int c4 = qd & 255;
  float cnt = counts[row];
  float4* p = (float4*)dout + qd;
  if (cnt > 0.f) {
    float4 v = *p;
    float inv = 1.0f / cnt;
    v.x *= inv; v.y *= inv; v.z *= inv; v.w *= inv;
    *p = v;
  } else {
    *p = ((const float4*)null_token)[c4];
  }
}

extern "C" void kernel_launch(void* const* d_in, const int* in_sizes, int n_in,
                              void* d_out, int out_size, void* d_ws, size_t ws_size,
                              hipStream_t stream) {
  const float* x = (const float*)d_in[0];
  const float* wqr = (const float*)d_in[1];
  const float* wkvr = (const float*)d_in[2];
  const float* wq = (const float*)d_in[3];
  const float* wkv = (const float*)d_in[4];
  const float* wout = (const float*)d_in[5];
  const float* nullkv = (const float*)d_in[6];
  const float* nulltok = (const float*)d_in[7];
  float* out = (float*)d_out;
  char* ws = (char*)d_ws;
  // workspace layout (bytes)
  float* qlog = (float*)(ws + 0);                  // 256 KB
  float* kvlog = (float*)(ws + 262144);            // 256 KB
  int* qidx = (int*)(ws + 524288);                 // 64 KB
  int* kvidx = (int*)(ws + 589824);                // 32 KB
  float* qscore = (float*)(ws + 622592);           // 64 KB
  float* kvscore = (float*)(ws + 688128);          // 32 KB
  float* counts = (float*)(ws + 720896);           // 64 KB
  u16* qbuf = (u16*)(ws + 786432);                 // 16 MB  [16][1024][512]
  u16* kbuf = (u16*)(ws + 17563648);               // 8 MB   [16][512][512]
  u16* vtbuf = (u16*)(ws + 25952256);              // 8 MB   [16][8][64][512]
  u16* obuf = (u16*)(ws + 34476032);               // 16 MB  [16][1024][512]
  u16* xbf = (u16*)(ws + 51253248);                // 32 MB  [4][4096][1024]
  u16* wqbf = (u16*)(ws + 84807680);               // 4 MB   [4][512][1024]
  u16* wkvbf = (u16*)(ws + 89001984);              // 8 MB   [4][1024][1024]
  u16* woutbf = (u16*)(ws + 97390592);             // 4 MB   [4][1024][512]
  // total ~101.6 MB

  hipMemsetAsync(counts, 0, 65536, stream);
  hipMemsetAsync(out, 0, (size_t)NB * SEQ * DM * 4, stream);
  convert_bf16<<<16384, 256, 0, stream>>>(x, xbf, 4194304);
  convert_bf16<<<2048, 256, 0, stream>>>(wq, wqbf, 524288);
  convert_bf16<<<4096, 256, 0, stream>>>(wkv, wkvbf, 1048576);
  convert_bf16<<<2048, 256, 0, stream>>>(wout, woutbf, 524288);
  router_kernel<<<4096, 256, 0, stream>>>(x, wqr, wkvr, qlog, kvlog);
  topk_kernel<<<16, 256, 0, stream>>>(qlog, NQS, qidx, qscore, counts);
  topk_kernel<<<16, 256, 0, stream>>>(kvlog, NKS, kvidx, kvscore, nullptr);
  gemm_qproj<<<dim3(4, 8, 16), 256, 0, stream>>>(xbf, qidx, wqbf, qbuf);
  gemm_kvproj<<<dim3(8, 4, 16), 256, 0, stream>>>(xbf, kvidx, wkvbf, kvscore, kbuf, vtbuf);
  attn_mfma<<<dim3(16, 8, 16), 256, 0, stream>>>(qbuf, kbuf, vtbuf, nullkv, obuf);
  gemm_outproj<<<dim3(8, 8, 16), 256, 0, stream>>>(obuf, woutbf, qidx, qscore, out);
  finalize_kernel<<<16384, 256, 0, stream>>>(out, counts, nulltok);
}

// Round 5
// 467.372 us; speedup vs baseline: 1.1481x; 1.1481x over previous
//
#include <hip/hip_runtime.h>
#include <math.h>

#define NB 4
#define SEQ 4096
#define DM 1024
#define NG 4
#define DI 512
#define NQS 1024
#define NKS 512
#define NHD 8
#define DHD 64

typedef unsigned int u32;
typedef unsigned short u16;
typedef __bf16 bf16x8 __attribute__((ext_vector_type(8)));
typedef float f32x4 __attribute__((ext_vector_type(4)));

__device__ __forceinline__ float bf2f(u16 u) { return __uint_as_float(((u32)u) << 16); }
__device__ __forceinline__ u16 f2bf(float f) {
  u32 u = __float_as_uint(f);
  u32 r = (u + 0x7FFFu + ((u >> 16) & 1u)) >> 16;
  return (u16)r;
}

// ---------------- fp32 -> bf16 bulk convert ----------------
__global__ __launch_bounds__(256) void convert_bf16(const float* __restrict__ src,
                                                    u16* __restrict__ dst, int n4) {
  int i = blockIdx.x * 256 + threadIdx.x;
  if (i < n4) {
    float4 v = ((const float4*)src)[i];
    ushort4 o;
    o.x = f2bf(v.x); o.y = f2bf(v.y); o.z = f2bf(v.z); o.w = f2bf(v.w);
    ((ushort4*)dst)[i] = o;
  }
}

// ---------------- router: logits[b][g][n] for q and kv (fp32 — selection exactness) ----------------
__global__ __launch_bounds__(256) void router_kernel(
    const float* __restrict__ x, const float* __restrict__ wqr,
    const float* __restrict__ wkvr, float* __restrict__ qlog,
    float* __restrict__ kvlog) {
  __shared__ float wsm[8192];
  int tid = threadIdx.x;
  for (int k = tid; k < 8192; k += 256)
    wsm[k] = (k < 4096) ? wqr[k] : wkvr[k - 4096];
  __syncthreads();
  int widx = blockIdx.x * 4 + (tid >> 6);
  int lane = tid & 63;
  int b = widx >> 12, tok = widx & 4095;
  const float4* xr = (const float4*)(x + ((size_t)(b * SEQ + tok)) * DM);
  float4 xv[4];
#pragma unroll
  for (int i = 0; i < 4; i++) xv[i] = xr[i * 64 + lane];
  float accs[8];
#pragma unroll
  for (int r = 0; r < 8; r++) {
    const float4* wr = (const float4*)(wsm + r * 1024);
    float a = 0.f;
#pragma unroll
    for (int i = 0; i < 4; i++) {
      float4 w4 = wr[i * 64 + lane];
      a += xv[i].x * w4.x + xv[i].y * w4.y + xv[i].z * w4.z + xv[i].w * w4.w;
    }
    accs[r] = a;
  }
#pragma unroll
  for (int r = 0; r < 8; r++) {
    float a = accs[r];
#pragma unroll
    for (int off = 32; off >= 1; off >>= 1) a += __shfl_xor(a, off);
    if (lane == 0) {
      if (r < 4) qlog[((b << 2) | r) * SEQ + tok] = a;
      else kvlog[((b << 2) | (r - 4)) * SEQ + tok] = a;
    }
  }
}

// ---------------- top-k radix select per (b,g) ----------------
__global__ __launch_bounds__(256) void topk_kernel(
    const float* __restrict__ logits, int K, int* __restrict__ out_idx,
    float* __restrict__ out_score, float* __restrict__ counts) {
  __shared__ u32 keys[4096];
  __shared__ int eqlist[2048];
  __shared__ int scnt[4];
  __shared__ int s_gt, s_eq;
  int bg = blockIdx.x;
  int tid = threadIdx.x;
  const float* L = logits + bg * 4096;
  for (int e = tid; e < 4096; e += 256) {
    u32 u = __float_as_uint(L[e]);
    keys[e] = (u >> 31) ? ~u : (u | 0x80000000u);
  }
  if (tid == 0) { s_gt = 0; s_eq = 0; }
  __syncthreads();
  u32 prefix = 0;
  int remaining = K;
  for (int bit = 31; bit >= 0; --bit) {
    u32 want = prefix | (1u << bit);
    u32 mask = ~((1u << bit) - 1u);
    int c = 0;
    for (int e = tid; e < 4096; e += 256) c += ((keys[e] & mask) == want) ? 1 : 0;
#pragma unroll
    for (int off = 32; off >= 1; off >>= 1) c += __shfl_xor(c, off);
    if ((tid & 63) == 0) scnt[tid >> 6] = c;
    __syncthreads();
    int total = scnt[0] + scnt[1] + scnt[2] + scnt[3];
    if (total >= remaining) prefix = want;
    else remaining -= total;
    __syncthreads();
  }
  u32 T = prefix;
  for (int e = tid; e < 4096; e += 256) {
    u32 k = keys[e];
    if (k > T) {
      int pos = atomicAdd(&s_gt, 1);
      out_idx[bg * K + pos] = e;
      float v = L[e];
      out_score[bg * K + pos] = 1.0f / (1.0f + __expf(-v));
      if (counts) atomicAdd(&counts[(bg >> 2) * SEQ + e], 1.0f);
    } else if (k == T) {
      int p = atomicAdd(&s_eq, 1);
      if (p < 2048) eqlist[p] = e;
    }
  }
  __syncthreads();
  int gt = s_gt;
  int eq = min(s_eq, 2048);
  int need = K - gt;
  for (int i = tid; i < eq; i += 256) {
    int my = eqlist[i];
    int rank = 0;
    for (int j = 0; j < eq; j++) rank += (eqlist[j] < my) ? 1 : 0;
    if (rank < need) {
      int pos = gt + rank;
      out_idx[bg * K + pos] = my;
      float v = L[my];
      out_score[bg * K + pos] = 1.0f / (1.0f + __expf(-v));
      if (counts) atomicAdd(&counts[(bg >> 2) * SEQ + my], 1.0f);
    }
  }
}

// ---------------- shared MFMA GEMM core: 128x128 tile, BK=64, swizzled LDS ----------------
struct Ptr4 { const u16* p[4]; };

__device__ __forceinline__ void mfma_core(Ptr4 A, Ptr4 B, u16* Asm, u16* Bsm,
                                          int ktiles, int tid, f32x4 (&acc)[4][4]) {
  int w = tid >> 6, lane = tid & 63;
  int col = lane & 15, quad = lane >> 4;
  int wr = w >> 1, wc = w & 1;
  for (int kt = 0; kt < ktiles; kt++) {
#pragma unroll
    for (int r = 0; r < 4; r++) {
      char* ldsA = (char*)Asm + (r * 256 + w * 64) * 16;
      __builtin_amdgcn_global_load_lds(
          (const __attribute__((address_space(1))) void*)(A.p[r] + kt * 64),
          (__attribute__((address_space(3))) void*)ldsA, 16, 0, 0);
    }
#pragma unroll
    for (int r = 0; r < 4; r++) {
      char* ldsB = (char*)Bsm + (r * 256 + w * 64) * 16;
      __builtin_amdgcn_global_load_lds(
          (const __attribute__((address_space(1))) void*)(B.p[r] + kt * 64),
          (__attribute__((address_space(3))) void*)ldsB, 16, 0, 0);
    }
    __syncthreads();
#pragma unroll
    for (int k04 = 0; k04 < 8; k04 += 4) {
      bf16x8 af[4], bfr[4];
#pragma unroll
      for (int t = 0; t < 4; t++) {
        int rowa = wr * 64 + t * 16 + col;
        int sp = (quad + k04) ^ (col & 7);
        af[t] = *(const bf16x8*)((const char*)Asm + (rowa * 8 + sp) * 16);
        int rowb = wc * 64 + t * 16 + col;
        bfr[t] = *(const bf16x8*)((const char*)Bsm + (rowb * 8 + sp) * 16);
      }
#pragma unroll
      for (int t = 0; t < 4; t++)
#pragma unroll
        for (int u = 0; u < 4; u++)
          acc[t][u] = __builtin_amdgcn_mfma_f32_16x16x32_bf16(af[t], bfr[u], acc[t][u], 0, 0, 0);
    }
    __syncthreads();
  }
}

// ---------------- q projection: qbuf[bg][1024][512] = gather(xbf) @ wq^T ----------------
__global__ __launch_bounds__(256) void gemm_qproj(
    const u16* __restrict__ xbf, const int* __restrict__ qidx,
    const u16* __restrict__ wqbf, u16* __restrict__ qbuf) {
  int bg = blockIdx.z, b = bg >> 2, g = bg & 3;
  int row0 = blockIdx.y * 128, col0 = blockIdx.x * 128;
  __shared__ __align__(16) u16 Asm[8192], Bsm[8192];
  __shared__ int ridx[128];
  int tid = threadIdx.x;
  if (tid < 128) ridx[tid] = qidx[bg * NQS + row0 + tid];
  __syncthreads();
  Ptr4 A, B;
#pragma unroll
  for (int r = 0; r < 4; r++) {
    int G = r * 256 + tid;
    int row = G >> 3;
    int seg = (G & 7) ^ (row & 7);
    A.p[r] = xbf + ((size_t)b * SEQ + ridx[row]) * DM + seg * 8;
    B.p[r] = wqbf + ((size_t)g * DI + col0 + row) * DM + seg * 8;
  }
  f32x4 acc[4][4] = {};
  mfma_core(A, B, Asm, Bsm, DM / 64, tid, acc);
  int w = tid >> 6, lane = tid & 63;
  int col = lane & 15, quad = lane >> 4;
  int wr = w >> 1, wc = w & 1;
#pragma unroll
  for (int t = 0; t < 4; t++)
#pragma unroll
    for (int u = 0; u < 4; u++)
#pragma unroll
      for (int r = 0; r < 4; r++) {
        int rowg = row0 + wr * 64 + t * 16 + quad * 4 + r;
        int colg = col0 + wc * 64 + u * 16 + col;
        qbuf[((size_t)bg * NQS + rowg) * DI + colg] = f2bf(acc[t][u][r]);
      }
}

// ---------------- kv projection: K -> kbuf, V^T (scaled) -> vtbuf[bg][h][64][512] ----------------
__global__ __launch_bounds__(256) void gemm_kvproj(
    const u16* __restrict__ xbf, const int* __restrict__ kvidx,
    const u16* __restrict__ wkvbf, const float* __restrict__ kvscore,
    u16* __restrict__ kbuf, u16* __restrict__ vtbuf) {
  int bg = blockIdx.z, b = bg >> 2, g = bg & 3;
  int row0 = blockIdx.y * 128, col0 = blockIdx.x * 128;
  __shared__ __align__(16) u16 Asm[8192], Bsm[8192];
  __shared__ int ridx[128];
  int tid = threadIdx.x;
  if (tid < 128) ridx[tid] = kvidx[bg * NKS + row0 + tid];
  __syncthreads();
  Ptr4 A, B;
#pragma unroll
  for (int r = 0; r < 4; r++) {
    int G = r * 256 + tid;
    int row = G >> 3;
    int seg = (G & 7) ^ (row & 7);
    A.p[r] = xbf + ((size_t)b * SEQ + ridx[row]) * DM + seg * 8;
    B.p[r] = wkvbf + ((size_t)g * (2 * DI) + col0 + row) * DM + seg * 8;
  }
  f32x4 acc[4][4] = {};
  mfma_core(A, B, Asm, Bsm, DM / 64, tid, acc);
  int w = tid >> 6, lane = tid & 63;
  int col = lane & 15, quad = lane >> 4;
  int wr = w >> 1, wc = w & 1;
  if (col0 < DI) {
#pragma unroll
    for (int t = 0; t < 4; t++)
#pragma unroll
      for (int u = 0; u < 4; u++)
#pragma unroll
        for (int r = 0; r < 4; r++) {
          int rowg = row0 + wr * 64 + t * 16 + quad * 4 + r;
          int colg = col0 + wc * 64 + u * 16 + col;
          kbuf[((size_t)bg * NKS + rowg) * DI + colg] = f2bf(acc[t][u][r]);
        }
  } else {
#pragma unroll
    for (int t = 0; t < 4; t++)
#pragma unroll
      for (int r = 0; r < 4; r++) {
        int rowg = row0 + wr * 64 + t * 16 + quad * 4 + r;  // key index 0..511
        float sc = kvscore[bg * NKS + rowg];
#pragma unroll
        for (int u = 0; u < 4; u++) {
          int vc = col0 - DI + wc * 64 + u * 16 + col;  // 0..511
          int h = vc >> 6, d = vc & 63;
          vtbuf[(((size_t)bg * NHD + h) * DHD + d) * NKS + rowg] =
              f2bf(acc[t][u][r] * sc);
        }
      }
  }
}

// ---------------- out projection + scaled scatter-add ----------------
__global__ __launch_bounds__(256) void gemm_outproj(
    const u16* __restrict__ obuf, const u16* __restrict__ woutbf,
    const int* __restrict__ qidx, const float* __restrict__ qscore,
    float* __restrict__ dout) {
  int bg = blockIdx.z, b = bg >> 2, g = bg & 3;
  int row0 = blockIdx.y * 128, col0 = blockIdx.x * 128;
  __shared__ __align__(16) u16 Asm[8192], Bsm[8192];
  int tid = threadIdx.x;
  Ptr4 A, B;
#pragma unroll
  for (int r = 0; r < 4; r++) {
    int G = r * 256 + tid;
    int row = G >> 3;
    int seg = (G & 7) ^ (row & 7);
    A.p[r] = obuf + ((size_t)bg * NQS + row0 + row) * DI + seg * 8;
    B.p[r] = woutbf + ((size_t)g * DM + col0 + row) * DI + seg * 8;
  }
  f32x4 acc[4][4] = {};
  mfma_core(A, B, Asm, Bsm, DI / 64, tid, acc);
  int w = tid >> 6, lane = tid & 63;
  int col = lane & 15, quad = lane >> 4;
  int wr = w >> 1, wc = w & 1;
#pragma unroll
  for (int t = 0; t < 4; t++)
#pragma unroll
    for (int r = 0; r < 4; r++) {
      int rowg = row0 + wr * 64 + t * 16 + quad * 4 + r;
      float sc = qscore[bg * NQS + rowg];
      int tok = qidx[bg * NQS + rowg];
      float* orow = dout + ((size_t)b * SEQ + tok) * DM;
#pragma unroll
      for (int u = 0; u < 4; u++) {
        int colg = col0 + wc * 64 + u * 16 + col;
        atomicAdd(&orow[colg], acc[t][u][r] * sc);
      }
    }
}

// ---------------- MFMA flash attention v3: LDS-staged K/V (swizzled, wide staging),
// null-KV folded into init, 4 chunks of 128 real keys, per-wave swizzled P slab ----------------
#define SM_SC 0.1803368801033677f  // 0.125 * log2(e)

__global__ __launch_bounds__(256) void attn_mfma(
    const u16* __restrict__ qbuf, const u16* __restrict__ kbuf,
    const u16* __restrict__ vtbuf, const float* __restrict__ null_kv,
    u16* __restrict__ obuf) {
  int qt = blockIdx.x;  // 0..15
  int h = blockIdx.y;   // 0..7
  int bg = blockIdx.z;  // 0..15
  int g = bg & 3;
  int tid = threadIdx.x;
  int w = tid >> 6, lane = tid & 63;
  int col = lane & 15, quad = lane >> 4;

  // Ks: 128 keys x 8 d-granules (16B), granule-swizzled: slot = key*8 + (j ^ (key&7))
  __shared__ __align__(16) u16 Ks[128 * 64];   // 16 KB
  // Vts: 64 d x 16 key-granules, slot = d*16 + ((j&8)|((j^(d&7))&7))
  __shared__ __align__(16) u16 Vts[64 * 128];  // 16 KB
  // per-wave P slab (r4 layout, proven low-conflict)
  __shared__ __align__(16) u16 Ps[4 * 256 * 8];  // 16 KB

  // Q A-fragments
  int q0 = qt * 64 + w * 16;
  const u16* qp = qbuf + ((size_t)bg * NQS + q0 + col) * DI + h * DHD + quad * 8;
  bf16x8 qa0 = *(const bf16x8*)qp;
  bf16x8 qa1 = *(const bf16x8*)(qp + 32);

  // ---- null-key init: m = q . k_null (raw), l = 1, O = v_null ----
  const float* nk = null_kv + ((0 * NG + g) * NHD + h) * DHD;
  const float* nv = null_kv + ((1 * NG + g) * NHD + h) * DHD;
  bf16x8 kn0, kn1;
#pragma unroll
  for (int j = 0; j < 8; j++) {
    ((u16*)&kn0)[j] = f2bf(nk[quad * 8 + j]);
    ((u16*)&kn1)[j] = f2bf(nk[32 + quad * 8 + j]);
  }
  f32x4 sn = {0.f, 0.f, 0.f, 0.f};
  sn = __builtin_amdgcn_mfma_f32_16x16x32_bf16(qa0, kn0, sn, 0, 0, 0);
  sn = __builtin_amdgcn_mfma_f32_16x16x32_bf16(qa1, kn1, sn, 0, 0, 0);

  f32x4 oacc[4];
  float m_run[4], l_run[4];
#pragma unroll
  for (int t = 0; t < 4; t++) {
    float v = nv[t * 16 + col];
#pragma unroll
    for (int r = 0; r < 4; r++) oacc[t][r] = v;
  }
#pragma unroll
  for (int r = 0; r < 4; r++) { m_run[r] = sn[r]; l_run[r] = 1.f; }

  const u16* kb_base = kbuf + (size_t)bg * NKS * DI + h * DHD;
  const u16* vt_base = vtbuf + (((size_t)bg * NHD + h) * DHD) * NKS;

  for (int c = 0; c < 4; c++) {
    int base = c * 128;
    // ---- stage K chunk via global_load_lds (coalesced, swizzled dest) ----
#pragma unroll
    for (int r = 0; r < 4; r++) {
      int G = r * 256 + tid;
      int key = G >> 3;
      int j = (G & 7) ^ (key & 7);
      __builtin_amdgcn_global_load_lds(
          (const __attribute__((address_space(1))) void*)(kb_base + (size_t)(base + key) * DI + j * 8),
          (__attribute__((address_space(3))) void*)((char*)Ks + (r * 256 + w * 64) * 16),
          16, 0, 0);
    }
    // ---- stage V^T chunk ----
#pragma unroll
    for (int r = 0; r < 4; r++) {
      int G = r * 256 + tid;
      int d = G >> 4;
      int sp0 = G & 15;
      int j = (sp0 & 8) | ((sp0 ^ (d & 7)) & 7);
      __builtin_amdgcn_global_load_lds(
          (const __attribute__((address_space(1))) void*)(vt_base + (size_t)d * NKS + base + j * 8),
          (__attribute__((address_space(3))) void*)((char*)Vts + (r * 256 + w * 64) * 16),
          16, 0, 0);
    }
    __syncthreads();

    // ---- S = Q K^T : 8 tiles of 16 keys, B-frags from swizzled LDS ----
    float sreg[8][4];
#pragma unroll
    for (int t = 0; t < 8; t++) {
      int key = t * 16 + col;
      bf16x8 kb0 = *(const bf16x8*)&Ks[(key * 8 + (quad ^ (key & 7))) * 8];
      bf16x8 kb1 = *(const bf16x8*)&Ks[(key * 8 + ((4 + quad) ^ (key & 7))) * 8];
      f32x4 s = {0.f, 0.f, 0.f, 0.f};
      s = __builtin_amdgcn_mfma_f32_16x16x32_bf16(qa0, kb0, s, 0, 0, 0);
      s = __builtin_amdgcn_mfma_f32_16x16x32_bf16(qa1, kb1, s, 0, 0, 0);
#pragma unroll
      for (int r = 0; r < 4; r++) sreg[t][r] = s[r];
    }

    // ---- online softmax (raw-score units; 0.125 folded into exp2 const) ----
    float alpha[4], rs[4];
#pragma unroll
    for (int r = 0; r < 4; r++) {
      float m = sreg[0][r];
#pragma unroll
      for (int t = 1; t < 8; t++) m = fmaxf(m, sreg[t][r]);
      m = fmaxf(m, __shfl_xor(m, 1));
      m = fmaxf(m, __shfl_xor(m, 2));
      m = fmaxf(m, __shfl_xor(m, 4));
      m = fmaxf(m, __shfl_xor(m, 8));
      float mnew = fmaxf(m_run[r], m);
      alpha[r] = exp2f((m_run[r] - mnew) * SM_SC);
      m_run[r] = mnew;
      rs[r] = 0.f;
    }
#pragma unroll
    for (int t = 0; t < 8; t++) {
      int key = t * 16 + col;
      int gg = key >> 3;
#pragma unroll
      for (int r = 0; r < 4; r++) {
        float p = exp2f((sreg[t][r] - m_run[r]) * SM_SC);
        rs[r] += p;
        int row = quad * 4 + r;
        int sp = (gg & 8) | ((gg ^ (row & 7)) & 7);
        Ps[((w * 256 + row * 16 + sp) << 3) | (key & 7)] = f2bf(p);
      }
    }
#pragma unroll
    for (int r = 0; r < 4; r++) {
      float s = rs[r];
      s += __shfl_xor(s, 1);
      s += __shfl_xor(s, 2);
      s += __shfl_xor(s, 4);
      s += __shfl_xor(s, 8);
      l_run[r] = l_run[r] * alpha[r] + s;
#pragma unroll
      for (int t = 0; t < 4; t++) oacc[t][r] *= alpha[r];
    }

    // ---- O += P V : A-frag from per-wave LDS, V B-frags from swizzled LDS ----
#pragma unroll
    for (int s = 0; s < 4; s++) {
      int gg = s * 4 + quad;
      int sp = (gg & 8) | ((gg ^ (col & 7)) & 7);
      bf16x8 pa = *(const bf16x8*)&Ps[(w * 256 + col * 16 + sp) << 3];
#pragma unroll
      for (int t = 0; t < 4; t++) {
        int d = t * 16 + col;
        int spv = (gg & 8) | ((gg ^ (d & 7)) & 7);
        bf16x8 vb = *(const bf16x8*)&Vts[(d * 16 + spv) * 8];
        oacc[t] = __builtin_amdgcn_mfma_f32_16x16x32_bf16(pa, vb, oacc[t], 0, 0, 0);
      }
    }
    __syncthreads();
  }

  // ---- epilogue: O / l, store bf16 ----
  float inv[4];
#pragma unroll
  for (int r = 0; r < 4; r++) inv[r] = 1.0f / l_run[r];
#pragma unroll
  for (int t = 0; t < 4; t++) {
#pragma unroll
    for (int r = 0; r < 4; r++) {
      obuf[((size_t)bg * NQS + q0 + quad * 4 + r) * DI + h * DHD + t * 16 + col] =
          f2bf(oacc[t][r] * inv[r]);
    }
  }
}

// ---------------- finalize: mean + null-token fill ----------------
__global__ __launch_bounds__(256) void finalize_kernel(
    float* __restrict__ dout, const float* __restrict__ counts,
    const float* __restrict__ null_token) {
  int qd = blockIdx.x * 256 + threadIdx.x;
  int row = qd >> 8;
  int c4 = qd & 255;
  float cnt = counts[row];
  float4* p = (float4*)dout + qd;
  if (cnt > 0.f) {
    float4 v = *p;
    float inv = 1.0f / cnt;
    v.x *= inv; v.y *= inv; v.z *= inv; v.w *= inv;
    *p = v;
  } else {
    *p = ((const float4*)null_token)[c4];
  }
}

extern "C" void kernel_launch(void* const* d_in, const int* in_sizes, int n_in,
                              void* d_out, int out_size, void* d_ws, size_t ws_size,
                              hipStream_t stream) {
  const float* x = (const float*)d_in[0];
  const float* wqr = (const float*)d_in[1];
  const float* wkvr = (const float*)d_in[2];
  const float* wq = (const float*)d_in[3];
  const float* wkv = (const float*)d_in[4];
  const float* wout = (const float*)d_in[5];
  const float* nullkv = (const float*)d_in[6];
  const float* nulltok = (const float*)d_in[7];
  float* out = (float*)d_out;
  char* ws = (char*)d_ws;
  // workspace layout (bytes)
  float* qlog = (float*)(ws + 0);                  // 256 KB
  float* kvlog = (float*)(ws + 262144);            // 256 KB
  int* qidx = (int*)(ws + 524288);                 // 64 KB
  int* kvidx = (int*)(ws + 589824);                // 32 KB
  float* qscore = (float*)(ws + 622592);           // 64 KB
  float* kvscore = (float*)(ws + 688128);          // 32 KB
  float* counts = (float*)(ws + 720896);           // 64 KB
  u16* qbuf = (u16*)(ws + 786432);                 // 16 MB  [16][1024][512]
  u16* kbuf = (u16*)(ws + 17563648);               // 8 MB   [16][512][512]
  u16* vtbuf = (u16*)(ws + 25952256);              // 8 MB   [16][8][64][512]
  u16* obuf = (u16*)(ws + 34476032);               // 16 MB  [16][1024][512]
  u16* xbf = (u16*)(ws + 51253248);                // 32 MB  [4][4096][1024]
  u16* wqbf = (u16*)(ws + 84807680);               // 4 MB   [4][512][1024]
  u16* wkvbf = (u16*)(ws + 89001984);              // 8 MB   [4][1024][1024]
  u16* woutbf = (u16*)(ws + 97390592);             // 4 MB   [4][1024][512]
  // total ~101.6 MB

  hipMemsetAsync(counts, 0, 65536, stream);
  hipMemsetAsync(out, 0, (size_t)NB * SEQ * DM * 4, stream);
  convert_bf16<<<16384, 256, 0, stream>>>(x, xbf, 4194304);
  convert_bf16<<<2048, 256, 0, stream>>>(wq, wqbf, 524288);
  convert_bf16<<<4096, 256, 0, stream>>>(wkv, wkvbf, 1048576);
  convert_bf16<<<2048, 256, 0, stream>>>(wout, woutbf, 524288);
  router_kernel<<<4096, 256, 0, stream>>>(x, wqr, wkvr, qlog, kvlog);
  topk_kernel<<<16, 256, 0, stream>>>(qlog, NQS, qidx, qscore, counts);
  topk_kernel<<<16, 256, 0, stream>>>(kvlog, NKS, kvidx, kvscore, nullptr);
  gemm_qproj<<<dim3(4, 8, 16), 256, 0, stream>>>(xbf, qidx, wqbf, qbuf);
  gemm_kvproj<<<dim3(8, 4, 16), 256, 0, stream>>>(xbf, kvidx, wkvbf, kvscore, kbuf, vtbuf);
  attn_mfma<<<dim3(16, 8, 16), 256, 0, stream>>>(qbuf, kbuf, vtbuf, nullkv, obuf);
  gemm_outproj<<<dim3(8, 8, 16), 256, 0, stream>>>(obuf, woutbf, qidx, qscore, out);
  finalize_kernel<<<16384, 256, 0, stream>>>(out, counts, nulltok);
}